// Round 1
// baseline (50.076 us; speedup 1.0000x reference)
//
#include <hip/hip_runtime.h>

#define NP 2990
#define NT 32
#define NC 21
#define NTHREADS 1024

// Segment boundaries: cumsum of SIZES[i]*BOXES[i] = 2166, 2766, 2916, 2970, 2986, 2990
__device__ __forceinline__ int segment_of(int p) {
    if (p < 2166) return 0;
    if (p < 2766) return 1;
    if (p < 2916) return 2;
    if (p < 2970) return 3;
    if (p < 2986) return 4;
    return 5;
}

__global__ __launch_bounds__(NTHREADS) void ssd_stats_kernel(
    const float* __restrict__ conf,     // conf_data[0] : [NP][NC]
    const float* __restrict__ priors,   // [NP][4] (cx,cy,w,h)
    const float* __restrict__ targets,  // targets[0] : [NT][5] (x1,y1,x2,y2,label)
    float* __restrict__ out)            // [6][4]
{
    __shared__ float s_ov[NP];    // best_truth_ov per prior
    __shared__ int   s_bti[NP];   // best_truth_idx per prior
    __shared__ float s_tr[NT * 5];
    __shared__ int   s_bpi[NT];   // best_prior_idx per truth
    __shared__ int   s_cnt[24];

    const int tid = threadIdx.x;

    if (tid < NT * 5) s_tr[tid] = targets[tid];
    if (tid < 24)     s_cnt[tid] = 0;
    __syncthreads();

    // ---- Phase A: per-prior best truth (argmax over 32 truths, first-max) ----
    for (int p = tid; p < NP; p += NTHREADS) {
        float4 pr = reinterpret_cast<const float4*>(priors)[p];
        float px1 = pr.x - pr.z * 0.5f;
        float py1 = pr.y - pr.w * 0.5f;
        float px2 = pr.x + pr.z * 0.5f;
        float py2 = pr.y + pr.w * 0.5f;
        float ab  = (px2 - px1) * (py2 - py1);
        float best = -1.0f; int bi = 0;
        #pragma unroll 4
        for (int t = 0; t < NT; ++t) {
            float tx1 = s_tr[t*5+0], ty1 = s_tr[t*5+1];
            float tx2 = s_tr[t*5+2], ty2 = s_tr[t*5+3];
            float ix = fmaxf(fminf(tx2, px2) - fmaxf(tx1, px1), 0.0f);
            float iy = fmaxf(fminf(ty2, py2) - fmaxf(ty1, py1), 0.0f);
            float inter = ix * iy;
            float aa = (tx2 - tx1) * (ty2 - ty1);
            float ov = inter / (aa + ab - inter);
            if (ov > best) { best = ov; bi = t; }   // strict > keeps first max
        }
        s_ov[p]  = best;
        s_bti[p] = bi;
    }
    __syncthreads();

    // ---- Phase B: per-truth best prior (argmax over 2990 priors, first-max) ----
    {
        const int wave = tid >> 6;
        const int lane = tid & 63;
        const int t0 = wave;        // truths 0..15
        const int t1 = wave + 16;   // truths 16..31

        float t0x1 = s_tr[t0*5+0], t0y1 = s_tr[t0*5+1], t0x2 = s_tr[t0*5+2], t0y2 = s_tr[t0*5+3];
        float t1x1 = s_tr[t1*5+0], t1y1 = s_tr[t1*5+1], t1x2 = s_tr[t1*5+2], t1y2 = s_tr[t1*5+3];
        float a0 = (t0x2 - t0x1) * (t0y2 - t0y1);
        float a1 = (t1x2 - t1x1) * (t1y2 - t1y1);

        float b0 = -1.0f, b1 = -1.0f;
        int   i0 = NP,    i1 = NP;

        for (int p = lane; p < NP; p += 64) {
            float4 pr = reinterpret_cast<const float4*>(priors)[p];
            float px1 = pr.x - pr.z * 0.5f;
            float py1 = pr.y - pr.w * 0.5f;
            float px2 = pr.x + pr.z * 0.5f;
            float py2 = pr.y + pr.w * 0.5f;
            float ab  = (px2 - px1) * (py2 - py1);

            float ix0 = fmaxf(fminf(t0x2, px2) - fmaxf(t0x1, px1), 0.0f);
            float iy0 = fmaxf(fminf(t0y2, py2) - fmaxf(t0y1, py1), 0.0f);
            float in0 = ix0 * iy0;
            float ov0 = in0 / (a0 + ab - in0);
            if (ov0 > b0) { b0 = ov0; i0 = p; }    // lane-local first max (p ascending)

            float ix1 = fmaxf(fminf(t1x2, px2) - fmaxf(t1x1, px1), 0.0f);
            float iy1 = fmaxf(fminf(t1y2, py2) - fmaxf(t1y1, py1), 0.0f);
            float in1 = ix1 * iy1;
            float ov1 = in1 / (a1 + ab - in1);
            if (ov1 > b1) { b1 = ov1; i1 = p; }
        }

        // 64-lane butterfly argmax reduce; min-index tie-break => global first-max
        #pragma unroll
        for (int off = 32; off > 0; off >>= 1) {
            float o0 = __shfl_xor(b0, off); int j0 = __shfl_xor(i0, off);
            if (o0 > b0 || (o0 == b0 && j0 < i0)) { b0 = o0; i0 = j0; }
            float o1 = __shfl_xor(b1, off); int j1 = __shfl_xor(i1, off);
            if (o1 > b1 || (o1 == b1 && j1 < i1)) { b1 = o1; i1 = j1; }
        }
        if (lane == 0) { s_bpi[t0] = i0; s_bpi[t1] = i1; }
    }
    __syncthreads();

    // ---- Phase C: sequential scatter (last-wins for duplicate best priors) ----
    if (tid == 0) {
        for (int t = 0; t < NT; ++t) {
            int p = s_bpi[t];
            s_ov[p]  = 2.0f;
            s_bti[p] = t;
        }
    }
    __syncthreads();

    // ---- Phase D: conf_t, pred argmax over 21 classes, segmented counters ----
    for (int p = tid; p < NP; p += NTHREADS) {
        int   bt = s_bti[p];
        float ov = s_ov[p];
        int ct = (ov < 0.5f) ? 0 : ((int)s_tr[bt*5+4] + 1);

        const float* cp = conf + p * NC;
        float best = cp[0]; int pred = 0;
        #pragma unroll
        for (int c = 1; c < NC; ++c) {
            float v = cp[c];
            if (v > best) { best = v; pred = c; }  // strict > keeps first max
        }

        int seg = segment_of(p);
        bool eq = (ct == pred);
        atomicAdd(&s_cnt[seg * 4 + (eq ? 0 : 1)], 1);
        if (ct > 0) atomicAdd(&s_cnt[seg * 4 + (eq ? 2 : 3)], 1);
    }
    __syncthreads();

    if (tid < 24) out[tid] = (float)s_cnt[tid];
}

extern "C" void kernel_launch(void* const* d_in, const int* in_sizes, int n_in,
                              void* d_out, int out_size, void* d_ws, size_t ws_size,
                              hipStream_t stream) {
    // Inputs (setup_inputs order): 0=loc_data (unused), 1=conf_data, 2=priors, 3=targets
    const float* conf    = (const float*)d_in[1];  // only batch 0 is read
    const float* priors  = (const float*)d_in[2];
    const float* targets = (const float*)d_in[3];  // only batch 0 is read
    float* out = (float*)d_out;

    hipLaunchKernelGGL(ssd_stats_kernel, dim3(1), dim3(NTHREADS), 0, stream,
                       conf, priors, targets, out);
}

// Round 2
// 22.188 us; speedup vs baseline: 2.2569x; 2.2569x over previous
//
#include <hip/hip_runtime.h>

#define NP 2990
#define NT 32
#define NC 21

// Segment boundaries: cumsum of SIZES[i]*BOXES[i] = 2166, 2766, 2916, 2970, 2986, 2990
__device__ __forceinline__ int segment_of(int p) {
    if (p < 2166) return 0;
    if (p < 2766) return 1;
    if (p < 2916) return 2;
    if (p < 2970) return 3;
    if (p < 2986) return 4;
    return 5;
}

// Workspace layout in d_ws
struct Ws {
    float ov[NP];    // best_truth_ov per prior (pre-scatter)
    int   bti[NP];   // best_truth_idx per prior (pre-scatter)
    int   pred[NP];  // argmax over 21 conf logits per prior
    int   bpi[NT];   // best_prior_idx per truth
};

// K1: blocks 0..11 (256 threads): per-prior best-truth + pred argmax.
//     blocks 12..19 (4 waves): one wave per truth, best-prior argmax.
__global__ __launch_bounds__(256) void k1_match(
    const float* __restrict__ conf,     // conf_data[0] : [NP][NC]
    const float* __restrict__ priors,   // [NP][4] (cx,cy,w,h)
    const float* __restrict__ targets,  // targets[0] : [NT][5]
    Ws* __restrict__ ws)
{
    const int b = blockIdx.x;

    if (b < 12) {
        __shared__ float s_tr[NT * 5];
        if (threadIdx.x < NT * 5) s_tr[threadIdx.x] = targets[threadIdx.x];
        __syncthreads();

        const int p = b * 256 + threadIdx.x;
        if (p < NP) {
            float4 pr = reinterpret_cast<const float4*>(priors)[p];
            float px1 = pr.x - pr.z * 0.5f;
            float py1 = pr.y - pr.w * 0.5f;
            float px2 = pr.x + pr.z * 0.5f;
            float py2 = pr.y + pr.w * 0.5f;
            float ab  = (px2 - px1) * (py2 - py1);

            float best = -1.0f; int bi = 0;
            #pragma unroll 4
            for (int t = 0; t < NT; ++t) {
                float tx1 = s_tr[t*5+0], ty1 = s_tr[t*5+1];
                float tx2 = s_tr[t*5+2], ty2 = s_tr[t*5+3];
                float ix = fmaxf(fminf(tx2, px2) - fmaxf(tx1, px1), 0.0f);
                float iy = fmaxf(fminf(ty2, py2) - fmaxf(ty1, py1), 0.0f);
                float inter = ix * iy;
                float aa = (tx2 - tx1) * (ty2 - ty1);
                float ov = inter / (aa + ab - inter);
                if (ov > best) { best = ov; bi = t; }   // strict > keeps first max
            }
            ws->ov[p]  = best;
            ws->bti[p] = bi;

            const float* cp = conf + p * NC;
            float bc = cp[0]; int pred = 0;
            #pragma unroll
            for (int c = 1; c < NC; ++c) {
                float v = cp[c];
                if (v > bc) { bc = v; pred = c; }       // strict > keeps first max
            }
            ws->pred[p] = pred;
        }
    } else {
        // one wave per truth: blocks 12..19 × 4 waves = 32 truths
        const int wave = threadIdx.x >> 6;
        const int lane = threadIdx.x & 63;
        const int t = (b - 12) * 4 + wave;

        const float tx1 = targets[t*5+0], ty1 = targets[t*5+1];
        const float tx2 = targets[t*5+2], ty2 = targets[t*5+3];
        const float aa  = (tx2 - tx1) * (ty2 - ty1);

        float best = -1.0f; int bi = NP;
        for (int p = lane; p < NP; p += 64) {
            float4 pr = reinterpret_cast<const float4*>(priors)[p];
            float px1 = pr.x - pr.z * 0.5f;
            float py1 = pr.y - pr.w * 0.5f;
            float px2 = pr.x + pr.z * 0.5f;
            float py2 = pr.y + pr.w * 0.5f;
            float ab  = (px2 - px1) * (py2 - py1);

            float ix = fmaxf(fminf(tx2, px2) - fmaxf(tx1, px1), 0.0f);
            float iy = fmaxf(fminf(ty2, py2) - fmaxf(ty1, py1), 0.0f);
            float inter = ix * iy;
            float ov = inter / (aa + ab - inter);
            if (ov > best) { best = ov; bi = p; }       // lane-local first max
        }

        // 64-lane butterfly argmax; min-index tie-break => global first-occurrence
        #pragma unroll
        for (int off = 32; off > 0; off >>= 1) {
            float o = __shfl_xor(best, off);
            int   j = __shfl_xor(bi,   off);
            if (o > best || (o == best && j < bi)) { best = o; bi = j; }
        }
        if (lane == 0) ws->bpi[t] = bi;
    }
}

// K2: single block — scatter (last-wins) + segmented counting.
__global__ __launch_bounds__(1024) void k2_count(
    const float* __restrict__ targets,
    const Ws* __restrict__ ws,
    float* __restrict__ out)
{
    __shared__ float s_ov[NP];
    __shared__ int   s_bti[NP];
    __shared__ float s_lab[NT];
    __shared__ int   s_bpi[NT];
    __shared__ int   s_cnt[24];

    const int tid = threadIdx.x;

    if (tid < NT) { s_lab[tid] = targets[tid*5+4]; s_bpi[tid] = ws->bpi[tid]; }
    if (tid < 24) s_cnt[tid] = 0;
    for (int p = tid; p < NP; p += 1024) { s_ov[p] = ws->ov[p]; s_bti[p] = ws->bti[p]; }
    __syncthreads();

    // sequential scatter: duplicates last-wins, matching .at[].set() loop semantics
    if (tid == 0) {
        for (int t = 0; t < NT; ++t) {
            int p = s_bpi[t];
            s_ov[p]  = 2.0f;
            s_bti[p] = t;
        }
    }
    __syncthreads();

    for (int p = tid; p < NP; p += 1024) {
        int ct = (s_ov[p] < 0.5f) ? 0 : ((int)s_lab[s_bti[p]] + 1);
        int pred = ws->pred[p];
        int seg = segment_of(p);
        bool eq = (ct == pred);
        atomicAdd(&s_cnt[seg * 4 + (eq ? 0 : 1)], 1);
        if (ct > 0) atomicAdd(&s_cnt[seg * 4 + (eq ? 2 : 3)], 1);
    }
    __syncthreads();

    if (tid < 24) out[tid] = (float)s_cnt[tid];
}

extern "C" void kernel_launch(void* const* d_in, const int* in_sizes, int n_in,
                              void* d_out, int out_size, void* d_ws, size_t ws_size,
                              hipStream_t stream) {
    // Inputs (setup_inputs order): 0=loc_data (unused), 1=conf_data, 2=priors, 3=targets
    const float* conf    = (const float*)d_in[1];  // only batch 0 is read
    const float* priors  = (const float*)d_in[2];
    const float* targets = (const float*)d_in[3];  // only batch 0 is read
    float* out = (float*)d_out;
    Ws* ws = (Ws*)d_ws;

    hipLaunchKernelGGL(k1_match, dim3(20), dim3(256), 0, stream, conf, priors, targets, ws);
    hipLaunchKernelGGL(k2_count, dim3(1), dim3(1024), 0, stream, targets, ws, out);
}